// Round 13
// baseline (382.293 us; speedup 1.0000x reference)
//
#include <hip/hip_runtime.h>
#include <cmath>

// Problem constants (from reference)
#define IN_DIM 128
#define HID 256
#define NHEADS 4
#define NGRAPHS 32

typedef unsigned short u16;
typedef __attribute__((ext_vector_type(8))) short bfrag8;   // 8 bf16 (4 VGPRs)
typedef __attribute__((ext_vector_type(4))) float f32x4;    // MFMA acc

// bf16 helpers (RNE)
__device__ __forceinline__ u16 f2bf(float x) {
  unsigned u = __float_as_uint(x);
  unsigned r = (u + 0x7fffu + ((u >> 16) & 1u)) >> 16;
  return (u16)r;
}
__device__ __forceinline__ float bf2f(u16 v) {
  return __uint_as_float(((unsigned)v) << 16);
}
__device__ __forceinline__ float lof(unsigned u) { return __uint_as_float(u << 16); }
__device__ __forceinline__ float hif(unsigned u) { return __uint_as_float(u & 0xffff0000u); }
__device__ __forceinline__ float lrelu02(float x) { return x > 0.f ? x : 0.2f * x; }

#define GACC(U, W)                                                   \
  acc[0] += (W) * lof((U).x); acc[1] += (W) * hif((U).x);            \
  acc[2] += (W) * lof((U).y); acc[3] += (W) * hif((U).y);            \
  acc[4] += (W) * lof((U).z); acc[5] += (W) * hif((U).z);            \
  acc[6] += (W) * lof((U).w); acc[7] += (W) * hif((U).w);

#define GACC2(U, W)                                                  \
  a0 += (W) * lof((U).x); a1 += (W) * hif((U).x);                    \
  a2 += (W) * lof((U).y); a3 += (W) * hif((U).y);

// ---------------------------------------------------------------------------
// CSR build
// ---------------------------------------------------------------------------
__global__ __launch_bounds__(256) void count_edges_k(const int* __restrict__ dst,
                                                     int* __restrict__ cnt, int E) {
  int i = blockIdx.x * 256 + threadIdx.x;
  if (i < E) atomicAdd(&cnt[dst[i]], 1);
}

__global__ __launch_bounds__(256) void fill_csr_k(const int* __restrict__ src,
                                                  const int* __restrict__ dst,
                                                  const int* __restrict__ row_ptr,
                                                  int* __restrict__ cursor,
                                                  int* __restrict__ csr_src, int E) {
  int i = blockIdx.x * 256 + threadIdx.x;
  if (i < E) {
    int d = dst[i];
    int p = atomicAdd(&cursor[d], 1);
    csr_src[row_ptr[d] + p] = src[i];
  }
}

// ---------------------------------------------------------------------------
// 256-thread exclusive scan over cnt -> row_ptr (+ dinv), run as prep block 0
// ---------------------------------------------------------------------------
__device__ void scan_dev(const int* __restrict__ cnt, int* __restrict__ row_ptr,
                         float* __restrict__ dinv, int n) {
  __shared__ int s_w[4];
  __shared__ int s_off[4];
  __shared__ int s_tot;
  int tid = threadIdx.x, wv = tid >> 6, lane = tid & 63;
  int carry = 0;
  int nch = (n + 255) >> 8;
  for (int c = 0; c < nch; c++) {
    int i = (c << 8) + tid;
    int v = (i < n) ? cnt[i] : 0;
    int incl = v;
    #pragma unroll
    for (int off = 1; off < 64; off <<= 1) {
      int t = __shfl_up(incl, off);
      if (lane >= off) incl += t;
    }
    if (lane == 63) s_w[wv] = incl;
    __syncthreads();
    if (tid == 0) {
      int a0 = s_w[0], a1 = s_w[1], a2 = s_w[2], a3 = s_w[3];
      s_off[0] = 0; s_off[1] = a0; s_off[2] = a0 + a1; s_off[3] = a0 + a1 + a2;
      s_tot = a0 + a1 + a2 + a3;
    }
    __syncthreads();
    int excl = incl - v + s_off[wv] + carry;
    if (i < n) {
      row_ptr[i] = excl;
      dinv[i] = rsqrtf((float)(v + 1));
    }
    carry += s_tot;
    __syncthreads();
  }
  if (tid == 0) row_ptr[n] = carry;
}

// ---------------------------------------------------------------------------
// Fused prep: scan (block 0) + pack x/W1/W2/Wg (MFMA frag order) + watt
// + tail block (graph bounds -> ginv, out := bias).
// Packed layout (u16): [(frag*KT + kt)*1024 + hl*512 + lane*8 + j]
// x is packed HI-ONLY (all GEMMs run 2-term: a_hi*b_hi + a_hi*b_lo).
// ---------------------------------------------------------------------------
template <bool LO>
__device__ void pack_a_dev(const float* __restrict__ A, u16* __restrict__ Ap,
                           int K, int KT, int wid, int lane) {
  int fm = wid / KT, kt = wid - fm * KT;
  int m = fm * 16 + (lane & 15);
  int kb = kt * 32 + (lane >> 4) * 8;
  const float* src = A + (size_t)m * K + kb;
  float4 v0 = *(const float4*)src;
  float4 v1 = *(const float4*)(src + 4);
  float vv[8] = {v0.x, v0.y, v0.z, v0.w, v1.x, v1.y, v1.z, v1.w};
  u16 hi[8];
  #pragma unroll
  for (int j = 0; j < 8; j++) hi[j] = f2bf(vv[j]);
  u16* dstp = Ap + ((size_t)fm * KT + kt) * 1024 + lane * 8;
  *(ushort4*)(dstp)     = make_ushort4(hi[0], hi[1], hi[2], hi[3]);
  *(ushort4*)(dstp + 4) = make_ushort4(hi[4], hi[5], hi[6], hi[7]);
  if constexpr (LO) {
    u16 lo[8];
    #pragma unroll
    for (int j = 0; j < 8; j++) lo[j] = f2bf(vv[j] - bf2f(hi[j]));
    *(ushort4*)(dstp + 512) = make_ushort4(lo[0], lo[1], lo[2], lo[3]);
    *(ushort4*)(dstp + 516) = make_ushort4(lo[4], lo[5], lo[6], lo[7]);
  }
}

__device__ void pack_b_dev(const float* __restrict__ B, u16* __restrict__ Bp,
                           int N, int KT, int wid, int lane) {
  int fn = wid / KT, kt = wid - fn * KT;
  int n = fn * 16 + (lane & 15);
  int kb = kt * 32 + (lane >> 4) * 8;
  float vv[8];
  #pragma unroll
  for (int j = 0; j < 8; j++) vv[j] = B[(size_t)(kb + j) * N + n];
  u16 hi[8], lo[8];
  #pragma unroll
  for (int j = 0; j < 8; j++) {
    u16 h = f2bf(vv[j]);
    hi[j] = h;
    lo[j] = f2bf(vv[j] - bf2f(h));
  }
  u16* dstp = Bp + ((size_t)fn * KT + kt) * 1024 + lane * 8;
  *(ushort4*)(dstp)       = make_ushort4(hi[0], hi[1], hi[2], hi[3]);
  *(ushort4*)(dstp + 4)   = make_ushort4(hi[4], hi[5], hi[6], hi[7]);
  *(ushort4*)(dstp + 512) = make_ushort4(lo[0], lo[1], lo[2], lo[3]);
  *(ushort4*)(dstp + 516) = make_ushort4(lo[4], lo[5], lo[6], lo[7]);
}

__global__ __launch_bounds__(256) void prep_k(const float* __restrict__ x,
                                              const float* __restrict__ W1,
                                              const float* __restrict__ W2,
                                              const float* __restrict__ Wg,
                                              const float* __restrict__ att_src,
                                              const float* __restrict__ att_dst,
                                              const int* __restrict__ cnt,
                                              int* __restrict__ row_ptr,
                                              float* __restrict__ dinv,
                                              u16* __restrict__ xp,
                                              u16* __restrict__ w1p,
                                              u16* __restrict__ w2p,
                                              u16* __restrict__ wgp,
                                              float* __restrict__ w_s,
                                              float* __restrict__ w_d,
                                              const int* __restrict__ batch,
                                              float* __restrict__ ginv,
                                              const float* __restrict__ b_heads,
                                              float* __restrict__ outp,
                                              int NFM, int N) {
  __shared__ float red_s[4][NHEADS];
  __shared__ float red_d[4][NHEADS];
  int b = blockIdx.x;
  int tid = threadIdx.x;
  int lane = tid & 63;
  if (b == 0) {
    scan_dev(cnt, row_ptr, dinv, N);
    return;
  }
  b -= 1;
  int XB = NFM;
  if (b < XB) {
    int wid = b * 4 + (tid >> 6);
    if (wid < NFM * 4) pack_a_dev<false>(x, xp, IN_DIM, 4, wid, lane);
  } else if (b < XB + 16) {
    pack_b_dev(W1, w1p, HID, 4, (b - XB) * 4 + (tid >> 6), lane);
  } else if (b < XB + 48) {
    pack_b_dev(W2, w2p, HID, 8, (b - XB - 16) * 4 + (tid >> 6), lane);
  } else if (b < XB + 176) {
    pack_b_dev(Wg, wgp, NHEADS * HID, 8, (b - XB - 48) * 4 + (tid >> 6), lane);
  } else if (b < XB + 432) {
    int k = b - (XB + 176);
    int c = tid, wvv = c >> 6, ln = c & 63;
    #pragma unroll
    for (int h = 0; h < NHEADS; h++) {
      float w = Wg[(size_t)k * (NHEADS * HID) + h * HID + c];
      float vs = w * att_src[h * HID + c];
      float vd = w * att_dst[h * HID + c];
      #pragma unroll
      for (int off = 32; off; off >>= 1) {
        vs += __shfl_xor(vs, off);
        vd += __shfl_xor(vd, off);
      }
      if (ln == 0) { red_s[wvv][h] = vs; red_d[wvv][h] = vd; }
    }
    __syncthreads();
    if (c < NHEADS)
      w_s[k * NHEADS + c] = red_s[0][c] + red_s[1][c] + red_s[2][c] + red_s[3][c];
    else if (c < 2 * NHEADS) {
      int h = c - NHEADS;
      w_d[k * NHEADS + h] = red_d[0][h] + red_d[1][h] + red_d[2][h] + red_d[3][h];
    }
  } else {
    // tail block: per-graph bounds -> ginv; out := bias
    __shared__ int s_b[NGRAPHS + 1];
    if (tid <= NGRAPHS) {
      int target = tid;
      int lo = 0, hi = N;
      while (lo < hi) {
        int mid = (lo + hi) >> 1;
        if (batch[mid] < target) lo = mid + 1; else hi = mid;
      }
      s_b[tid] = lo;
    }
    __syncthreads();
    if (tid < NGRAPHS)
      ginv[tid] = 1.f / fmaxf((float)(s_b[tid + 1] - s_b[tid]), 1.f);
    if (tid < NGRAPHS * 4) outp[tid] = b_heads[tid & 3];
  }
}

// ---------------------------------------------------------------------------
// 2-term split-bf16 MFMA GEMM (a_hi*b_hi + a_hi*b_lo), pre-packed operands,
// no LDS / no barriers.  Block = 4 waves (2x2); block tile 64x64.
// ---------------------------------------------------------------------------
template <int KT, int LDC>
__global__ __launch_bounds__(256) void mfma_gemm_k(const u16* __restrict__ Ap,
                                                   const u16* __restrict__ Bp,
                                                   u16* __restrict__ Cb, int M) {
  int tid = threadIdx.x;
  int w = tid >> 6, lane = tid & 63;
  int wm = w >> 1, wn = w & 1;
  int fm0 = blockIdx.y * 4 + wm * 2;
  int fn0 = blockIdx.x * 4 + wn * 2;
  f32x4 acc[2][2] = {};
  #pragma unroll
  for (int kt = 0; kt < KT; kt++) {
    bfrag8 a_hi[2], b_hi[2], b_lo[2];
    #pragma unroll
    for (int f = 0; f < 2; f++) {
      const u16* pa = Ap + ((size_t)(fm0 + f) * KT + kt) * 1024 + lane * 8;
      a_hi[f] = *(const bfrag8*)pa;
      const u16* pb = Bp + ((size_t)(fn0 + f) * KT + kt) * 1024 + lane * 8;
      b_hi[f] = *(const bfrag8*)pb;
      b_lo[f] = *(const bfrag8*)(pb + 512);
    }
    #pragma unroll
    for (int f = 0; f < 2; f++) {
      #pragma unroll
      for (int g = 0; g < 2; g++) {
        acc[f][g] = __builtin_amdgcn_mfma_f32_16x16x32_bf16(a_hi[f], b_hi[g], acc[f][g], 0, 0, 0);
        acc[f][g] = __builtin_amdgcn_mfma_f32_16x16x32_bf16(a_hi[f], b_lo[g], acc[f][g], 0, 0, 0);
      }
    }
  }
  int r0 = (lane >> 4) * 4;
  int cl = lane & 15;
  #pragma unroll
  for (int f = 0; f < 2; f++) {
    #pragma unroll
    for (int g = 0; g < 2; g++) {
      int col = (fn0 + g) * 16 + cl;
      #pragma unroll
      for (int r = 0; r < 4; r++) {
        int row = (fm0 + f) * 16 + r0 + r;
        if (row < M) Cb[(size_t)row * LDC + col] = f2bf(acc[f][g][r]);
      }
    }
  }
}

// ---------------------------------------------------------------------------
// GCN aggregation, one WAVE per node: lane owns 4 channels (uint2 bf16),
// unroll-4 edge gather.  v = relu(agg + b); packed bf16 (hi only) out;
// LOGITS fused for layer 2.
// ---------------------------------------------------------------------------
template <bool LOGITS>
__global__ __launch_bounds__(256) void gcn_agg_k(const u16* __restrict__ t,
                                                 const int* __restrict__ row_ptr,
                                                 const int* __restrict__ csr_src,
                                                 const float* __restrict__ dinv,
                                                 const float* __restrict__ bias,
                                                 u16* __restrict__ apack,
                                                 const float* __restrict__ w_s,
                                                 const float* __restrict__ w_d,
                                                 float4* __restrict__ a_src4,
                                                 float4* __restrict__ a_dst4, int N) {
  int wv = threadIdx.x >> 6, lane = threadIdx.x & 63;
  int i = blockIdx.x * 4 + wv;
  if (i >= N) return;
  float di = dinv[i];
  int c4 = lane * 4;
  int beg = row_ptr[i], end = row_ptr[i + 1];
  float a0, a1, a2, a3;
  {  // self loop
    uint2 u = *(const uint2*)&t[(size_t)i * HID + c4];
    float w = di * di;
    a0 = w * lof(u.x); a1 = w * hif(u.x); a2 = w * lof(u.y); a3 = w * hif(u.y);
  }
  int e = beg;
  for (; e + 3 < end; e += 4) {
    int s0 = csr_src[e + 0], s1 = csr_src[e + 1];
    int s2 = csr_src[e + 2], s3 = csr_src[e + 3];
    float w0 = dinv[s0] * di, w1 = dinv[s1] * di;
    float w2 = dinv[s2] * di, w3 = dinv[s3] * di;
    uint2 u0 = *(const uint2*)&t[(size_t)s0 * HID + c4];
    uint2 u1 = *(const uint2*)&t[(size_t)s1 * HID + c4];
    uint2 u2 = *(const uint2*)&t[(size_t)s2 * HID + c4];
    uint2 u3 = *(const uint2*)&t[(size_t)s3 * HID + c4];
    GACC2(u0, w0); GACC2(u1, w1); GACC2(u2, w2); GACC2(u3, w3);
  }
  for (; e < end; e++) {
    int s = csr_src[e];
    float w = dinv[s] * di;
    uint2 u = *(const uint2*)&t[(size_t)s * HID + c4];
    GACC2(u, w);
  }
  float4 bv = *(const float4*)&bias[c4];
  float v0 = fmaxf(a0 + bv.x, 0.f), v1 = fmaxf(a1 + bv.y, 0.f);
  float v2 = fmaxf(a2 + bv.z, 0.f), v3 = fmaxf(a3 + bv.w, 0.f);
  // pack bf16 hi (KT=8 layout)
  {
    int fm = i >> 4, kt = c4 >> 5;
    int pl = (i & 15) + 16 * ((c4 >> 3) & 3);
    int j = c4 & 7;
    size_t base = ((size_t)fm * 8 + kt) * 1024 + pl * 8 + j;
    *(ushort4*)&apack[base] = make_ushort4(f2bf(v0), f2bf(v1), f2bf(v2), f2bf(v3));
  }
  if constexpr (LOGITS) {
    const float4* ws4 = (const float4*)w_s;
    const float4* wd4 = (const float4*)w_d;
    float4 s0 = ws4[c4 + 0], s1 = ws4[c4 + 1], s2 = ws4[c4 + 2], s3 = ws4[c4 + 3];
    float4 d0 = wd4[c4 + 0], d1 = wd4[c4 + 1], d2 = wd4[c4 + 2], d3 = wd4[c4 + 3];
    float ps0 = v0 * s0.x + v1 * s1.x + v2 * s2.x + v3 * s3.x;
    float ps1 = v0 * s0.y + v1 * s1.y + v2 * s2.y + v3 * s3.y;
    float ps2 = v0 * s0.z + v1 * s1.z + v2 * s2.z + v3 * s3.z;
    float ps3 = v0 * s0.w + v1 * s1.w + v2 * s2.w + v3 * s3.w;
    float pd0 = v0 * d0.x + v1 * d1.x + v2 * d2.x + v3 * d3.x;
    float pd1 = v0 * d0.y + v1 * d1.y + v2 * d2.y + v3 * d3.y;
    float pd2 = v0 * d0.z + v1 * d1.z + v2 * d2.z + v3 * d3.z;
    float pd3 = v0 * d0.w + v1 * d1.w + v2 * d2.w + v3 * d3.w;
    #pragma unroll
    for (int off = 32; off; off >>= 1) {
      ps0 += __shfl_xor(ps0, off); ps1 += __shfl_xor(ps1, off);
      ps2 += __shfl_xor(ps2, off); ps3 += __shfl_xor(ps3, off);
      pd0 += __shfl_xor(pd0, off); pd1 += __shfl_xor(pd1, off);
      pd2 += __shfl_xor(pd2, off); pd3 += __shfl_xor(pd3, off);
    }
    if (lane == 0) {
      a_src4[i] = make_float4(ps0, ps1, ps2, ps3);
      a_dst4[i] = make_float4(pd0, pd1, pd2, pd3);
    }
  }
}

// ---------------------------------------------------------------------------
// GAT aggregation + FUSED mean-pool + head projection.
// TWO waves per node, node-major hgT [n][1024] bf16, unroll 4.
// Epilogue: relu -> dot with W_heads -> 32-lane reduce -> 4 atomicAdds
// scaled by precomputed 1/cnt_g.  out pre-initialized with bias (prep tail).
// ---------------------------------------------------------------------------
__global__ __launch_bounds__(256) void gat_agg_k(const u16* __restrict__ hgT,
                                                 const int* __restrict__ row_ptr,
                                                 const int* __restrict__ csr_src,
                                                 const float4* __restrict__ a_src4,
                                                 const float4* __restrict__ a_dst4,
                                                 const float* __restrict__ bg,
                                                 const float* __restrict__ W_heads,
                                                 const float* __restrict__ ginv,
                                                 const int* __restrict__ batch,
                                                 float* __restrict__ outp, int N) {
  __shared__ int s_src[4][64];
  __shared__ float s_al[4][2][64];
  __shared__ float s_comb[2][32][9];
  int wv = threadIdx.x >> 6, lane = threadIdx.x & 63;
  int nodeSlot = wv >> 1, half = wv & 1;
  int i = blockIdx.x * 2 + nodeSlot;
  if (i >= N) { __syncthreads(); return; }
  int beg = row_ptr[i], end = row_ptr[i + 1];
  int deg = end - beg;
  float4 ad = a_dst4[i];
  int hsel = lane >> 5;
  const u16* rowbase = hgT + half * 512 + lane * 8;
  float acc[8];
  #pragma unroll
  for (int j = 0; j < 8; j++) acc[j] = 0.f;

  if (deg <= 63) {
    int s = (lane < deg) ? csr_src[beg + lane] : i;
    bool valid = (lane <= deg);
    float4 as = a_src4[s];
    float l0 = valid ? lrelu02(as.x + ad.x) : -INFINITY;
    float l1 = valid ? lrelu02(as.y + ad.y) : -INFINITY;
    float l2 = valid ? lrelu02(as.z + ad.z) : -INFINITY;
    float l3 = valid ? lrelu02(as.w + ad.w) : -INFINITY;
    float m0 = l0, m1 = l1, m2 = l2, m3 = l3;
    #pragma unroll
    for (int off = 32; off; off >>= 1) {
      m0 = fmaxf(m0, __shfl_xor(m0, off)); m1 = fmaxf(m1, __shfl_xor(m1, off));
      m2 = fmaxf(m2, __shfl_xor(m2, off)); m3 = fmaxf(m3, __shfl_xor(m3, off));
    }
    float e0 = valid ? expf(l0 - m0) : 0.f;
    float e1 = valid ? expf(l1 - m1) : 0.f;
    float e2 = valid ? expf(l2 - m2) : 0.f;
    float e3 = valid ? expf(l3 - m3) : 0.f;
    float z0 = e0, z1 = e1, z2 = e2, z3 = e3;
    #pragma unroll
    for (int off = 32; off; off >>= 1) {
      z0 += __shfl_xor(z0, off); z1 += __shfl_xor(z1, off);
      z2 += __shfl_xor(z2, off); z3 += __shfl_xor(z3, off);
    }
    s_src[wv][lane] = s;
    if (half == 0) {
      s_al[wv][0][lane] = e0 / (z0 + 1e-16f);
      s_al[wv][1][lane] = e1 / (z1 + 1e-16f);
    } else {
      s_al[wv][0][lane] = e2 / (z2 + 1e-16f);
      s_al[wv][1][lane] = e3 / (z3 + 1e-16f);
    }
    int nk = deg + 1;
    int e = 0;
    for (; e + 3 < nk; e += 4) {
      int sa = s_src[wv][e + 0], sb = s_src[wv][e + 1];
      int sc = s_src[wv][e + 2], sd = s_src[wv][e + 3];
      float wa = s_al[wv][hsel][e + 0], wb = s_al[wv][hsel][e + 1];
      float wc = s_al[wv][hsel][e + 2], wd = s_al[wv][hsel][e + 3];
      uint4 ua = *(const uint4*)(rowbase + (size_t)sa * 1024);
      uint4 ub = *(const uint4*)(rowbase + (size_t)sb * 1024);
      uint4 uc = *(const uint4*)(rowbase + (size_t)sc * 1024);
      uint4 ud = *(const uint4*)(rowbase + (size_t)sd * 1024);
      GACC(ua, wa); GACC(ub, wb); GACC(uc, wc); GACC(ud, wd);
    }
    for (; e < nk; e++) {
      int sa = s_src[wv][e];
      float wa = s_al[wv][hsel][e];
      uint4 ua = *(const uint4*)(rowbase + (size_t)sa * 1024);
      GACC(ua, wa);
    }
  } else {
    // generic path (deg > 63)
    float4 asi = a_src4[i];
    float ls0 = lrelu02(asi.x + ad.x), ls1 = lrelu02(asi.y + ad.y);
    float ls2 = lrelu02(asi.z + ad.z), ls3 = lrelu02(asi.w + ad.w);
    float m0 = ls0, m1 = ls1, m2 = ls2, m3 = ls3;
    for (int e = beg + lane; e < end; e += 64) {
      float4 as = a_src4[csr_src[e]];
      m0 = fmaxf(m0, lrelu02(as.x + ad.x)); m1 = fmaxf(m1, lrelu02(as.y + ad.y));
      m2 = fmaxf(m2, lrelu02(as.z + ad.z)); m3 = fmaxf(m3, lrelu02(as.w + ad.w));
    }
    #pragma unroll
    for (int off = 32; off; off >>= 1) {
      m0 = fmaxf(m0, __shfl_xor(m0, off)); m1 = fmaxf(m1, __shfl_xor(m1, off));
      m2 = fmaxf(m2, __shfl_xor(m2, off)); m3 = fmaxf(m3, __shfl_xor(m3, off));
    }
    float z0 = (lane == 0) ? expf(ls0 - m0) : 0.f;
    float z1 = (lane == 0) ? expf(ls1 - m1) : 0.f;
    float z2 = (lane == 0) ? expf(ls2 - m2) : 0.f;
    float z3 = (lane == 0) ? expf(ls3 - m3) : 0.f;
    for (int e = beg + lane; e < end; e += 64) {
      float4 as = a_src4[csr_src[e]];
      z0 += expf(lrelu02(as.x + ad.x) - m0); z1 += expf(lrelu02(as.y + ad.y) - m1);
      z2 += expf(lrelu02(as.z + ad.z) - m2); z3 += expf(lrelu02(as.w + ad.w) - m3);
    }
    #pragma unroll
    for (int off = 32; off; off >>= 1) {
      z0 += __shfl_xor(z0, off); z1 += __shfl_xor(z1, off);
      z2 += __shfl_xor(z2, off); z3 += __shfl_xor(z3, off);
    }
    float iz0 = 1.f / (z0 + 1e-16f), iz1 = 1.f / (z1 + 1e-16f);
    float iz2 = 1.f / (z2 + 1e-16f), iz3 = 1.f / (z3 + 1e-16f);
    {
      float w0 = expf(ls0 - m0) * iz0, w1 = expf(ls1 - m1) * iz1;
      float w2 = expf(ls2 - m2) * iz2, w3 = expf(ls3 - m3) * iz3;
      float aw = (half == 0) ? (hsel == 0 ? w0 : w1) : (hsel == 0 ? w2 : w3);
      uint4 u = *(const uint4*)(rowbase + (size_t)i * 1024);
      GACC(u, aw);
    }
    for (int base = beg; base < end; base += 64) {
      int mc = min(64, end - base);
      if (lane < mc) {
        int s = csr_src[base + lane];
        float4 as = a_src4[s];
        s_src[wv][lane] = s;
        if (half == 0) {
          s_al[wv][0][lane] = expf(lrelu02(as.x + ad.x) - m0) * iz0;
          s_al[wv][1][lane] = expf(lrelu02(as.y + ad.y) - m1) * iz1;
        } else {
          s_al[wv][0][lane] = expf(lrelu02(as.z + ad.z) - m2) * iz2;
          s_al[wv][1][lane] = expf(lrelu02(as.w + ad.w) - m3) * iz3;
        }
      }
      for (int e = 0; e < mc; e++) {
        int sa = s_src[wv][e];
        float wa = s_al[wv][hsel][e];
        uint4 ua = *(const uint4*)(rowbase + (size_t)sa * 1024);
        GACC(ua, wa);
      }
    }
  }
  #pragma unroll
  for (int j = 0; j < 8; j++) acc[j] += __shfl_xor(acc[j], 32);
  if (half == 1 && lane < 32) {
    #pragma unroll
    for (int j = 0; j < 8; j++) s_comb[nodeSlot][lane][j] = acc[j];
  }
  __syncthreads();
  if (half == 0 && lane < 32) {
    int cb = lane * 8;
    float p0 = 0.f, p1 = 0.f, p2 = 0.f, p3 = 0.f;
    #pragma unroll
    for (int j = 0; j < 8; j++) {
      float o = fmaxf((acc[j] + s_comb[nodeSlot][lane][j]) * 0.25f + bg[cb + j], 0.f);
      float4 wh = *(const float4*)&W_heads[(cb + j) * 4];
      p0 += o * wh.x; p1 += o * wh.y; p2 += o * wh.z; p3 += o * wh.w;
    }
    #pragma unroll
    for (int off = 16; off; off >>= 1) {
      p0 += __shfl_xor(p0, off); p1 += __shfl_xor(p1, off);
      p2 += __shfl_xor(p2, off); p3 += __shfl_xor(p3, off);
    }
    if (lane == 0) {
      int g = batch[i];
      float iv = ginv[g];
      atomicAdd(&outp[g * 4 + 0], p0 * iv);
      atomicAdd(&outp[g * 4 + 1], p1 * iv);
      atomicAdd(&outp[g * 4 + 2], p2 * iv);
      atomicAdd(&outp[g * 4 + 3], p3 * iv);
    }
  }
}

// ---------------------------------------------------------------------------
extern "C" void kernel_launch(void* const* d_in, const int* in_sizes, int n_in,
                              void* d_out, int out_size, void* d_ws, size_t ws_size,
                              hipStream_t stream) {
  const float* x = (const float*)d_in[0];
  const int* ei = (const int*)d_in[1];
  const int* batch = (const int*)d_in[2];
  const float* W1 = (const float*)d_in[3];
  const float* b1 = (const float*)d_in[4];
  const float* W2 = (const float*)d_in[5];
  const float* b2 = (const float*)d_in[6];
  const float* Wg = (const float*)d_in[7];
  const float* att_src = (const float*)d_in[8];
  const float* att_dst = (const float*)d_in[9];
  const float* bg = (const float*)d_in[10];
  const float* W_heads = (const float*)d_in[11];
  const float* b_heads = (const float*)d_in[12];
  float* out = (float*)d_out;

  const int N = in_sizes[0] / IN_DIM;   // 10000
  const int E = in_sizes[1] / 2;        // 160000
  const int* src = ei;
  const int* dst = ei + E;

  const int NFM = N / 16;               // 625
  const int NFMP = ((N + 63) / 64) * 4; // 628

  // workspace layout (256B aligned); cnt|cursor contiguous for 1 memset
  char* ws = (char*)d_ws;
  size_t off = 0;
  auto take = [&](size_t bytes) -> char* {
    char* p = ws + off;
    off = (off + bytes + 255) & ~(size_t)255;
    return p;
  };
  int* cnt      = (int*)take((size_t)N * 4);
  int* cursor   = (int*)take((size_t)N * 4);
  size_t zero_span = off;
  int* row_ptr  = (int*)take((size_t)(N + 1) * 4);
  int* csr_src  = (int*)take((size_t)E * 4);
  float* dinv   = (float*)take((size_t)N * 4);
  float4* a_src4 = (float4*)take((size_t)N * 16);
  float4* a_dst4 = (float4*)take((size_t)N * 16);
  float* w_s    = (float*)take((size_t)HID * NHEADS * 4);
  float* w_d    = (float*)take((size_t)HID * NHEADS * 4);
  float* ginv   = (float*)take((size_t)NGRAPHS * 4);
  u16*   tb     = (u16*)take((size_t)N * HID * 2);
  u16*   hgT    = (u16*)take((size_t)N * NHEADS * HID * 2);   // node-major [n][1024]
  u16*   xp     = (u16*)take((size_t)NFMP * 4 * 1024 * 2);
  u16*   h1p    = (u16*)take((size_t)NFMP * 8 * 1024 * 2);
  u16*   h2p    = (u16*)take((size_t)NFMP * 8 * 1024 * 2);
  u16*   w1p    = (u16*)take((size_t)16 * 4 * 1024 * 2);
  u16*   w2p    = (u16*)take((size_t)16 * 8 * 1024 * 2);
  u16*   wgp    = (u16*)take((size_t)64 * 8 * 1024 * 2);

  hipMemsetAsync(cnt, 0, zero_span, stream);

  int eb = (E + 255) / 256;
  count_edges_k<<<eb, 256, 0, stream>>>(dst, cnt, E);
  // prep: block0 = scan, then packs + watt + tail (ginv + out:=bias)
  prep_k<<<1 + NFM + 432 + 1, 256, 0, stream>>>(x, W1, W2, Wg, att_src, att_dst,
                                                cnt, row_ptr, dinv,
                                                xp, w1p, w2p, wgp, w_s, w_d,
                                                batch, ginv, b_heads, out, NFM, N);
  fill_csr_k<<<eb, 256, 0, stream>>>(src, dst, row_ptr, cursor, csr_src, E);

  int mg64 = (N + 63) / 64;
  int ng4 = (N + 3) / 4;
  int ng2 = (N + 1) / 2;
  // layer 1
  mfma_gemm_k<4, HID><<<dim3(4, mg64), 256, 0, stream>>>(xp, w1p, tb, N);
  gcn_agg_k<false><<<ng4, 256, 0, stream>>>(tb, row_ptr, csr_src, dinv, b1,
                                            h1p, nullptr, nullptr, nullptr, nullptr, N);
  // layer 2 (+ fused logits)
  mfma_gemm_k<8, HID><<<dim3(4, mg64), 256, 0, stream>>>(h1p, w2p, tb, N);
  gcn_agg_k<true><<<ng4, 256, 0, stream>>>(tb, row_ptr, csr_src, dinv, b2,
                                           h2p, w_s, w_d, a_src4, a_dst4, N);
  // GAT (hg GEMM + aggregation with fused pool/head)
  mfma_gemm_k<8, NHEADS * HID><<<dim3(16, mg64), 256, 0, stream>>>(h2p, wgp, hgT, N);
  gat_agg_k<<<ng2, 256, 0, stream>>>(hgT, row_ptr, csr_src, a_src4, a_dst4, bg,
                                     W_heads, ginv, batch, out, N);
}

// Round 14
// 191.643 us; speedup vs baseline: 1.9948x; 1.9948x over previous
//
#include <hip/hip_runtime.h>
#include <cmath>

// Problem constants (from reference)
#define IN_DIM 128
#define HID 256
#define NHEADS 4
#define NGRAPHS 32

typedef unsigned short u16;
typedef __attribute__((ext_vector_type(8))) short bfrag8;   // 8 bf16 (4 VGPRs)
typedef __attribute__((ext_vector_type(4))) float f32x4;    // MFMA acc

// bf16 helpers (RNE)
__device__ __forceinline__ u16 f2bf(float x) {
  unsigned u = __float_as_uint(x);
  unsigned r = (u + 0x7fffu + ((u >> 16) & 1u)) >> 16;
  return (u16)r;
}
__device__ __forceinline__ float bf2f(u16 v) {
  return __uint_as_float(((unsigned)v) << 16);
}
__device__ __forceinline__ float lof(unsigned u) { return __uint_as_float(u << 16); }
__device__ __forceinline__ float hif(unsigned u) { return __uint_as_float(u & 0xffff0000u); }
__device__ __forceinline__ float lrelu02(float x) { return x > 0.f ? x : 0.2f * x; }

#define GACC(U, W)                                                   \
  acc[0] += (W) * lof((U).x); acc[1] += (W) * hif((U).x);            \
  acc[2] += (W) * lof((U).y); acc[3] += (W) * hif((U).y);            \
  acc[4] += (W) * lof((U).z); acc[5] += (W) * hif((U).z);            \
  acc[6] += (W) * lof((U).w); acc[7] += (W) * hif((U).w);

#define GACC2(U, W)                                                  \
  a0 += (W) * lof((U).x); a1 += (W) * hif((U).x);                    \
  a2 += (W) * lof((U).y); a3 += (W) * hif((U).y);

// ---------------------------------------------------------------------------
// CSR build
// ---------------------------------------------------------------------------
__global__ __launch_bounds__(256) void count_edges_k(const int* __restrict__ dst,
                                                     int* __restrict__ cnt, int E) {
  int i = blockIdx.x * 256 + threadIdx.x;
  if (i < E) atomicAdd(&cnt[dst[i]], 1);
}

__global__ __launch_bounds__(256) void fill_csr_k(const int* __restrict__ src,
                                                  const int* __restrict__ dst,
                                                  const int* __restrict__ row_ptr,
                                                  int* __restrict__ cursor,
                                                  int* __restrict__ csr_src, int E) {
  int i = blockIdx.x * 256 + threadIdx.x;
  if (i < E) {
    int d = dst[i];
    int p = atomicAdd(&cursor[d], 1);
    csr_src[row_ptr[d] + p] = src[i];
  }
}

// ---------------------------------------------------------------------------
// 256-thread exclusive scan over cnt -> row_ptr (+ dinv), run as prep block 0
// ---------------------------------------------------------------------------
__device__ void scan_dev(const int* __restrict__ cnt, int* __restrict__ row_ptr,
                         float* __restrict__ dinv, int n) {
  __shared__ int s_w[4];
  __shared__ int s_off[4];
  __shared__ int s_tot;
  int tid = threadIdx.x, wv = tid >> 6, lane = tid & 63;
  int carry = 0;
  int nch = (n + 255) >> 8;
  for (int c = 0; c < nch; c++) {
    int i = (c << 8) + tid;
    int v = (i < n) ? cnt[i] : 0;
    int incl = v;
    #pragma unroll
    for (int off = 1; off < 64; off <<= 1) {
      int t = __shfl_up(incl, off);
      if (lane >= off) incl += t;
    }
    if (lane == 63) s_w[wv] = incl;
    __syncthreads();
    if (tid == 0) {
      int a0 = s_w[0], a1 = s_w[1], a2 = s_w[2], a3 = s_w[3];
      s_off[0] = 0; s_off[1] = a0; s_off[2] = a0 + a1; s_off[3] = a0 + a1 + a2;
      s_tot = a0 + a1 + a2 + a3;
    }
    __syncthreads();
    int excl = incl - v + s_off[wv] + carry;
    if (i < n) {
      row_ptr[i] = excl;
      dinv[i] = rsqrtf((float)(v + 1));
    }
    carry += s_tot;
    __syncthreads();
  }
  if (tid == 0) row_ptr[n] = carry;
}

// ---------------------------------------------------------------------------
// Fused prep: scan (block 0) + pack x/W1/W2/Wg (MFMA frag order) + watt
// + tail block (out := bias).
// Packed layout (u16): [(frag*KT + kt)*1024 + hl*512 + lane*8 + j]
// x is packed HI-ONLY (all GEMMs run 2-term: a_hi*b_hi + a_hi*b_lo).
// ---------------------------------------------------------------------------
__device__ void pack_a_dev(const float* __restrict__ A, u16* __restrict__ Ap,
                           int K, int KT, int wid, int lane) {
  int fm = wid / KT, kt = wid - fm * KT;
  int m = fm * 16 + (lane & 15);
  int kb = kt * 32 + (lane >> 4) * 8;
  const float* src = A + (size_t)m * K + kb;
  float4 v0 = *(const float4*)src;
  float4 v1 = *(const float4*)(src + 4);
  float vv[8] = {v0.x, v0.y, v0.z, v0.w, v1.x, v1.y, v1.z, v1.w};
  u16 hi[8];
  #pragma unroll
  for (int j = 0; j < 8; j++) hi[j] = f2bf(vv[j]);
  u16* dstp = Ap + ((size_t)fm * KT + kt) * 1024 + lane * 8;
  *(ushort4*)(dstp)     = make_ushort4(hi[0], hi[1], hi[2], hi[3]);
  *(ushort4*)(dstp + 4) = make_ushort4(hi[4], hi[5], hi[6], hi[7]);
}

__device__ void pack_b_dev(const float* __restrict__ B, u16* __restrict__ Bp,
                           int N, int KT, int wid, int lane) {
  int fn = wid / KT, kt = wid - fn * KT;
  int n = fn * 16 + (lane & 15);
  int kb = kt * 32 + (lane >> 4) * 8;
  float vv[8];
  #pragma unroll
  for (int j = 0; j < 8; j++) vv[j] = B[(size_t)(kb + j) * N + n];
  u16 hi[8], lo[8];
  #pragma unroll
  for (int j = 0; j < 8; j++) {
    u16 h = f2bf(vv[j]);
    hi[j] = h;
    lo[j] = f2bf(vv[j] - bf2f(h));
  }
  u16* dstp = Bp + ((size_t)fn * KT + kt) * 1024 + lane * 8;
  *(ushort4*)(dstp)       = make_ushort4(hi[0], hi[1], hi[2], hi[3]);
  *(ushort4*)(dstp + 4)   = make_ushort4(hi[4], hi[5], hi[6], hi[7]);
  *(ushort4*)(dstp + 512) = make_ushort4(lo[0], lo[1], lo[2], lo[3]);
  *(ushort4*)(dstp + 516) = make_ushort4(lo[4], lo[5], lo[6], lo[7]);
}

__global__ __launch_bounds__(256) void prep_k(const float* __restrict__ x,
                                              const float* __restrict__ W1,
                                              const float* __restrict__ W2,
                                              const float* __restrict__ Wg,
                                              const float* __restrict__ att_src,
                                              const float* __restrict__ att_dst,
                                              const int* __restrict__ cnt,
                                              int* __restrict__ row_ptr,
                                              float* __restrict__ dinv,
                                              u16* __restrict__ xp,
                                              u16* __restrict__ w1p,
                                              u16* __restrict__ w2p,
                                              u16* __restrict__ wgp,
                                              float* __restrict__ w_s,
                                              float* __restrict__ w_d,
                                              const float* __restrict__ b_heads,
                                              float* __restrict__ outp,
                                              int NFM, int N) {
  __shared__ float red_s[4][NHEADS];
  __shared__ float red_d[4][NHEADS];
  int b = blockIdx.x;
  int tid = threadIdx.x;
  int lane = tid & 63;
  if (b == 0) {
    scan_dev(cnt, row_ptr, dinv, N);
    return;
  }
  b -= 1;
  int XB = NFM;
  if (b < XB) {
    int wid = b * 4 + (tid >> 6);
    if (wid < NFM * 4) pack_a_dev(x, xp, IN_DIM, 4, wid, lane);
  } else if (b < XB + 16) {
    pack_b_dev(W1, w1p, HID, 4, (b - XB) * 4 + (tid >> 6), lane);
  } else if (b < XB + 48) {
    pack_b_dev(W2, w2p, HID, 8, (b - XB - 16) * 4 + (tid >> 6), lane);
  } else if (b < XB + 176) {
    pack_b_dev(Wg, wgp, NHEADS * HID, 8, (b - XB - 48) * 4 + (tid >> 6), lane);
  } else if (b < XB + 432) {
    int k = b - (XB + 176);
    int c = tid, wvv = c >> 6, ln = c & 63;
    #pragma unroll
    for (int h = 0; h < NHEADS; h++) {
      float w = Wg[(size_t)k * (NHEADS * HID) + h * HID + c];
      float vs = w * att_src[h * HID + c];
      float vd = w * att_dst[h * HID + c];
      #pragma unroll
      for (int off = 32; off; off >>= 1) {
        vs += __shfl_xor(vs, off);
        vd += __shfl_xor(vd, off);
      }
      if (ln == 0) { red_s[wvv][h] = vs; red_d[wvv][h] = vd; }
    }
    __syncthreads();
    if (c < NHEADS)
      w_s[k * NHEADS + c] = red_s[0][c] + red_s[1][c] + red_s[2][c] + red_s[3][c];
    else if (c < 2 * NHEADS) {
      int h = c - NHEADS;
      w_d[k * NHEADS + h] = red_d[0][h] + red_d[1][h] + red_d[2][h] + red_d[3][h];
    }
  } else {
    // tail block: out := bias
    if (tid < NGRAPHS * 4) outp[tid] = b_heads[tid & 3];
  }
}

// ---------------------------------------------------------------------------
// 2-term split-bf16 MFMA GEMM (a_hi*b_hi + a_hi*b_lo), pre-packed operands,
// no LDS / no barriers.  Block = 4 waves (2x2); block tile 64x64.
// ---------------------------------------------------------------------------
template <int KT, int LDC>
__global__ __launch_bounds__(256) void mfma_gemm_k(const u16* __restrict__ Ap,
                                                   const u16* __restrict__ Bp,
                                                   u16* __restrict__ Cb, int M) {
  int tid = threadIdx.x;
  int w = tid >> 6, lane = tid & 63;
  int wm = w >> 1, wn = w & 1;
  int fm0 = blockIdx.y * 4 + wm * 2;
  int fn0 = blockIdx.x * 4 + wn * 2;
  f32x4 acc[2][2] = {};
  #pragma unroll
  for (int kt = 0; kt < KT; kt++) {
    bfrag8 a_hi[2], b_hi[2], b_lo[2];
    #pragma unroll
    for (int f = 0; f < 2; f++) {
      const u16* pa = Ap + ((size_t)(fm0 + f) * KT + kt) * 1024 + lane * 8;
      a_hi[f] = *(const bfrag8*)pa;
      const u16* pb = Bp + ((size_t)(fn0 + f) * KT + kt) * 1024 + lane * 8;
      b_hi[f] = *(const bfrag8*)pb;
      b_lo[f] = *(const bfrag8*)(pb + 512);
    }
    #pragma unroll
    for (int f = 0; f < 2; f++) {
      #pragma unroll
      for (int g = 0; g < 2; g++) {
        acc[f][g] = __builtin_amdgcn_mfma_f32_16x16x32_bf16(a_hi[f], b_hi[g], acc[f][g], 0, 0, 0);
        acc[f][g] = __builtin_amdgcn_mfma_f32_16x16x32_bf16(a_hi[f], b_lo[g], acc[f][g], 0, 0, 0);
      }
    }
  }
  int r0 = (lane >> 4) * 4;
  int cl = lane & 15;
  #pragma unroll
  for (int f = 0; f < 2; f++) {
    #pragma unroll
    for (int g = 0; g < 2; g++) {
      int col = (fn0 + g) * 16 + cl;
      #pragma unroll
      for (int r = 0; r < 4; r++) {
        int row = (fm0 + f) * 16 + r0 + r;
        if (row < M) Cb[(size_t)row * LDC + col] = f2bf(acc[f][g][r]);
      }
    }
  }
}

// ---------------------------------------------------------------------------
// GCN aggregation, one WAVE per node: lane owns 4 channels (uint2 bf16),
// unroll-4 edge gather.  v = relu(agg + b); packed bf16 (hi only) out;
// LOGITS fused for layer 2.
// ---------------------------------------------------------------------------
template <bool LOGITS>
__global__ __launch_bounds__(256) void gcn_agg_k(const u16* __restrict__ t,
                                                 const int* __restrict__ row_ptr,
                                                 const int* __restrict__ csr_src,
                                                 const float* __restrict__ dinv,
                                                 const float* __restrict__ bias,
                                                 u16* __restrict__ apack,
                                                 const float* __restrict__ w_s,
                                                 const float* __restrict__ w_d,
                                                 float4* __restrict__ a_src4,
                                                 float4* __restrict__ a_dst4, int N) {
  int wv = threadIdx.x >> 6, lane = threadIdx.x & 63;
  int i = blockIdx.x * 4 + wv;
  if (i >= N) return;
  float di = dinv[i];
  int c4 = lane * 4;
  int beg = row_ptr[i], end = row_ptr[i + 1];
  float a0, a1, a2, a3;
  {  // self loop
    uint2 u = *(const uint2*)&t[(size_t)i * HID + c4];
    float w = di * di;
    a0 = w * lof(u.x); a1 = w * hif(u.x); a2 = w * lof(u.y); a3 = w * hif(u.y);
  }
  int e = beg;
  for (; e + 3 < end; e += 4) {
    int s0 = csr_src[e + 0], s1 = csr_src[e + 1];
    int s2 = csr_src[e + 2], s3 = csr_src[e + 3];
    float w0 = dinv[s0] * di, w1 = dinv[s1] * di;
    float w2 = dinv[s2] * di, w3 = dinv[s3] * di;
    uint2 u0 = *(const uint2*)&t[(size_t)s0 * HID + c4];
    uint2 u1 = *(const uint2*)&t[(size_t)s1 * HID + c4];
    uint2 u2 = *(const uint2*)&t[(size_t)s2 * HID + c4];
    uint2 u3 = *(const uint2*)&t[(size_t)s3 * HID + c4];
    GACC2(u0, w0); GACC2(u1, w1); GACC2(u2, w2); GACC2(u3, w3);
  }
  for (; e < end; e++) {
    int s = csr_src[e];
    float w = dinv[s] * di;
    uint2 u = *(const uint2*)&t[(size_t)s * HID + c4];
    GACC2(u, w);
  }
  float4 bv = *(const float4*)&bias[c4];
  float v0 = fmaxf(a0 + bv.x, 0.f), v1 = fmaxf(a1 + bv.y, 0.f);
  float v2 = fmaxf(a2 + bv.z, 0.f), v3 = fmaxf(a3 + bv.w, 0.f);
  // pack bf16 hi (KT=8 layout)
  {
    int fm = i >> 4, kt = c4 >> 5;
    int pl = (i & 15) + 16 * ((c4 >> 3) & 3);
    int j = c4 & 7;
    size_t base = ((size_t)fm * 8 + kt) * 1024 + pl * 8 + j;
    *(ushort4*)&apack[base] = make_ushort4(f2bf(v0), f2bf(v1), f2bf(v2), f2bf(v3));
  }
  if constexpr (LOGITS) {
    const float4* ws4 = (const float4*)w_s;
    const float4* wd4 = (const float4*)w_d;
    float4 s0 = ws4[c4 + 0], s1 = ws4[c4 + 1], s2 = ws4[c4 + 2], s3 = ws4[c4 + 3];
    float4 d0 = wd4[c4 + 0], d1 = wd4[c4 + 1], d2 = wd4[c4 + 2], d3 = wd4[c4 + 3];
    float ps0 = v0 * s0.x + v1 * s1.x + v2 * s2.x + v3 * s3.x;
    float ps1 = v0 * s0.y + v1 * s1.y + v2 * s2.y + v3 * s3.y;
    float ps2 = v0 * s0.z + v1 * s1.z + v2 * s2.z + v3 * s3.z;
    float ps3 = v0 * s0.w + v1 * s1.w + v2 * s2.w + v3 * s3.w;
    float pd0 = v0 * d0.x + v1 * d1.x + v2 * d2.x + v3 * d3.x;
    float pd1 = v0 * d0.y + v1 * d1.y + v2 * d2.y + v3 * d3.y;
    float pd2 = v0 * d0.z + v1 * d1.z + v2 * d2.z + v3 * d3.z;
    float pd3 = v0 * d0.w + v1 * d1.w + v2 * d2.w + v3 * d3.w;
    #pragma unroll
    for (int off = 32; off; off >>= 1) {
      ps0 += __shfl_xor(ps0, off); ps1 += __shfl_xor(ps1, off);
      ps2 += __shfl_xor(ps2, off); ps3 += __shfl_xor(ps3, off);
      pd0 += __shfl_xor(pd0, off); pd1 += __shfl_xor(pd1, off);
      pd2 += __shfl_xor(pd2, off); pd3 += __shfl_xor(pd3, off);
    }
    if (lane == 0) {
      a_src4[i] = make_float4(ps0, ps1, ps2, ps3);
      a_dst4[i] = make_float4(pd0, pd1, pd2, pd3);
    }
  }
}

// ---------------------------------------------------------------------------
// GAT aggregation, TWO waves per node, node-major hgT [n][1024] bf16.
// Wave half h owns heads {2h, 2h+1}: 1 uint4 load per edge per lane,
// unroll 4.  Softmax (4 heads) redundant per wave in registers.
// Writes h3 (no atomics).
// ---------------------------------------------------------------------------
__global__ __launch_bounds__(256) void gat_agg_k(const u16* __restrict__ hgT,
                                                 const int* __restrict__ row_ptr,
                                                 const int* __restrict__ csr_src,
                                                 const float4* __restrict__ a_src4,
                                                 const float4* __restrict__ a_dst4,
                                                 const float* __restrict__ bg,
                                                 float* __restrict__ out, int N) {
  __shared__ int s_src[4][64];
  __shared__ float s_al[4][2][64];
  __shared__ float s_comb[2][32][9];
  int wv = threadIdx.x >> 6, lane = threadIdx.x & 63;
  int nodeSlot = wv >> 1, half = wv & 1;
  int i = blockIdx.x * 2 + nodeSlot;
  if (i >= N) { __syncthreads(); return; }
  int beg = row_ptr[i], end = row_ptr[i + 1];
  int deg = end - beg;
  float4 ad = a_dst4[i];
  int hsel = lane >> 5;
  const u16* rowbase = hgT + half * 512 + lane * 8;
  float acc[8];
  #pragma unroll
  for (int j = 0; j < 8; j++) acc[j] = 0.f;

  if (deg <= 63) {
    int s = (lane < deg) ? csr_src[beg + lane] : i;
    bool valid = (lane <= deg);
    float4 as = a_src4[s];
    float l0 = valid ? lrelu02(as.x + ad.x) : -INFINITY;
    float l1 = valid ? lrelu02(as.y + ad.y) : -INFINITY;
    float l2 = valid ? lrelu02(as.z + ad.z) : -INFINITY;
    float l3 = valid ? lrelu02(as.w + ad.w) : -INFINITY;
    float m0 = l0, m1 = l1, m2 = l2, m3 = l3;
    #pragma unroll
    for (int off = 32; off; off >>= 1) {
      m0 = fmaxf(m0, __shfl_xor(m0, off)); m1 = fmaxf(m1, __shfl_xor(m1, off));
      m2 = fmaxf(m2, __shfl_xor(m2, off)); m3 = fmaxf(m3, __shfl_xor(m3, off));
    }
    float e0 = valid ? expf(l0 - m0) : 0.f;
    float e1 = valid ? expf(l1 - m1) : 0.f;
    float e2 = valid ? expf(l2 - m2) : 0.f;
    float e3 = valid ? expf(l3 - m3) : 0.f;
    float z0 = e0, z1 = e1, z2 = e2, z3 = e3;
    #pragma unroll
    for (int off = 32; off; off >>= 1) {
      z0 += __shfl_xor(z0, off); z1 += __shfl_xor(z1, off);
      z2 += __shfl_xor(z2, off); z3 += __shfl_xor(z3, off);
    }
    s_src[wv][lane] = s;
    if (half == 0) {
      s_al[wv][0][lane] = e0 / (z0 + 1e-16f);
      s_al[wv][1][lane] = e1 / (z1 + 1e-16f);
    } else {
      s_al[wv][0][lane] = e2 / (z2 + 1e-16f);
      s_al[wv][1][lane] = e3 / (z3 + 1e-16f);
    }
    int nk = deg + 1;
    int e = 0;
    for (; e + 3 < nk; e += 4) {
      int sa = s_src[wv][e + 0], sb = s_src[wv][e + 1];
      int sc = s_src[wv][e + 2], sd = s_src[wv][e + 3];
      float wa = s_al[wv][hsel][e + 0], wb = s_al[wv][hsel][e + 1];
      float wc = s_al[wv][hsel][e + 2], wd = s_al[wv][hsel][e + 3];
      uint4 ua = *(const uint4*)(rowbase + (size_t)sa * 1024);
      uint4 ub = *(const uint4*)(rowbase + (size_t)sb * 1024);
      uint4 uc = *(const uint4*)(rowbase + (size_t)sc * 1024);
      uint4 ud = *(const uint4*)(rowbase + (size_t)sd * 1024);
      GACC(ua, wa); GACC(ub, wb); GACC(uc, wc); GACC(ud, wd);
    }
    for (; e < nk; e++) {
      int sa = s_src[wv][e];
      float wa = s_al[wv][hsel][e];
      uint4 ua = *(const uint4*)(rowbase + (size_t)sa * 1024);
      GACC(ua, wa);
    }
  } else {
    // generic path (deg > 63)
    float4 asi = a_src4[i];
    float ls0 = lrelu02(asi.x + ad.x), ls1 = lrelu02(asi.y + ad.y);
    float ls2 = lrelu02(asi.z + ad.z), ls3 = lrelu02(asi.w + ad.w);
    float m0 = ls0, m1 = ls1, m2 = ls2, m3 = ls3;
    for (int e = beg + lane; e < end; e += 64) {
      float4 as = a_src4[csr_src[e]];
      m0 = fmaxf(m0, lrelu02(as.x + ad.x)); m1 = fmaxf(m1, lrelu02(as.y + ad.y));
      m2 = fmaxf(m2, lrelu02(as.z + ad.z)); m3 = fmaxf(m3, lrelu02(as.w + ad.w));
    }
    #pragma unroll
    for (int off = 32; off; off >>= 1) {
      m0 = fmaxf(m0, __shfl_xor(m0, off)); m1 = fmaxf(m1, __shfl_xor(m1, off));
      m2 = fmaxf(m2, __shfl_xor(m2, off)); m3 = fmaxf(m3, __shfl_xor(m3, off));
    }
    float z0 = (lane == 0) ? expf(ls0 - m0) : 0.f;
    float z1 = (lane == 0) ? expf(ls1 - m1) : 0.f;
    float z2 = (lane == 0) ? expf(ls2 - m2) : 0.f;
    float z3 = (lane == 0) ? expf(ls3 - m3) : 0.f;
    for (int e = beg + lane; e < end; e += 64) {
      float4 as = a_src4[csr_src[e]];
      z0 += expf(lrelu02(as.x + ad.x) - m0); z1 += expf(lrelu02(as.y + ad.y) - m1);
      z2 += expf(lrelu02(as.z + ad.z) - m2); z3 += expf(lrelu02(as.w + ad.w) - m3);
    }
    #pragma unroll
    for (int off = 32; off; off >>= 1) {
      z0 += __shfl_xor(z0, off); z1 += __shfl_xor(z1, off);
      z2 += __shfl_xor(z2, off); z3 += __shfl_xor(z3, off);
    }
    float iz0 = 1.f / (z0 + 1e-16f), iz1 = 1.f / (z1 + 1e-16f);
    float iz2 = 1.f / (z2 + 1e-16f), iz3 = 1.f / (z3 + 1e-16f);
    {
      float w0 = expf(ls0 - m0) * iz0, w1 = expf(ls1 - m1) * iz1;
      float w2 = expf(ls2 - m2) * iz2, w3 = expf(ls3 - m3) * iz3;
      float aw = (half == 0) ? (hsel == 0 ? w0 : w1) : (hsel == 0 ? w2 : w3);
      uint4 u = *(const uint4*)(rowbase + (size_t)i * 1024);
      GACC(u, aw);
    }
    for (int base = beg; base < end; base += 64) {
      int mc = min(64, end - base);
      if (lane < mc) {
        int s = csr_src[base + lane];
        float4 as = a_src4[s];
        s_src[wv][lane] = s;
        if (half == 0) {
          s_al[wv][0][lane] = expf(lrelu02(as.x + ad.x) - m0) * iz0;
          s_al[wv][1][lane] = expf(lrelu02(as.y + ad.y) - m1) * iz1;
        } else {
          s_al[wv][0][lane] = expf(lrelu02(as.z + ad.z) - m2) * iz2;
          s_al[wv][1][lane] = expf(lrelu02(as.w + ad.w) - m3) * iz3;
        }
      }
      for (int e = 0; e < mc; e++) {
        int sa = s_src[wv][e];
        float wa = s_al[wv][hsel][e];
        uint4 ua = *(const uint4*)(rowbase + (size_t)sa * 1024);
        GACC(ua, wa);
      }
    }
  }
  #pragma unroll
  for (int j = 0; j < 8; j++) acc[j] += __shfl_xor(acc[j], 32);
  if (half == 1 && lane < 32) {
    #pragma unroll
    for (int j = 0; j < 8; j++) s_comb[nodeSlot][lane][j] = acc[j];
  }
  __syncthreads();
  if (half == 0 && lane < 32) {
    int cb = lane * 8;
    float o[8];
    #pragma unroll
    for (int j = 0; j < 8; j++)
      o[j] = fmaxf((acc[j] + s_comb[nodeSlot][lane][j]) * 0.25f + bg[cb + j], 0.f);
    float* op = out + (size_t)i * HID + cb;
    *(float4*)(op + 0) = make_float4(o[0], o[1], o[2], o[3]);
    *(float4*)(op + 4) = make_float4(o[4], o[5], o[6], o[7]);
  }
}

// ---------------------------------------------------------------------------
// Fused mean-pool + head GEMM.  Grid = NGRAPHS x 8 parts; block (g,part)
// binary-searches graph g's [i0,i1), strided-sums its part, dots with
// W_heads in-block, atomicAdds 4 floats (out pre-set to bias by prep tail).
// ---------------------------------------------------------------------------
__global__ __launch_bounds__(256) void pool_head_k(const float* __restrict__ h3,
                                                   const int* __restrict__ batch,
                                                   const float* __restrict__ W_heads,
                                                   float* __restrict__ out, int N) {
  int g = blockIdx.x >> 3;
  int part = blockIdx.x & 7;
  int c = threadIdx.x;
  __shared__ int s_bounds[2];
  if (c < 2) {
    int target = g + c;
    int lo = 0, hi = N;
    while (lo < hi) {
      int mid = (lo + hi) >> 1;
      if (batch[mid] < target) lo = mid + 1; else hi = mid;
    }
    s_bounds[c] = lo;
  }
  __syncthreads();
  int i0 = s_bounds[0], i1 = s_bounds[1];
  float acc0 = 0.f, acc1 = 0.f;
  int i = i0 + part;
  for (; i + 8 < i1; i += 16) {
    acc0 += h3[(size_t)i * HID + c];
    acc1 += h3[(size_t)(i + 8) * HID + c];
  }
  if (i < i1) acc0 += h3[(size_t)i * HID + c];
  float acc = acc0 + acc1;
  float invc = 1.f / fmaxf((float)(i1 - i0), 1.f);
  float4 wh = *(const float4*)&W_heads[c * 4];
  float p0 = acc * wh.x, p1 = acc * wh.y, p2 = acc * wh.z, p3 = acc * wh.w;
  int lane = c & 63, wv = c >> 6;
  #pragma unroll
  for (int off = 32; off; off >>= 1) {
    p0 += __shfl_xor(p0, off); p1 += __shfl_xor(p1, off);
    p2 += __shfl_xor(p2, off); p3 += __shfl_xor(p3, off);
  }
  __shared__ float s_red[4][4];
  if (lane == 0) { s_red[wv][0] = p0; s_red[wv][1] = p1; s_red[wv][2] = p2; s_red[wv][3] = p3; }
  __syncthreads();
  if (c < 4) {
    float r = s_red[0][c] + s_red[1][c] + s_red[2][c] + s_red[3][c];
    atomicAdd(&out[g * 4 + c], r * invc);
  }
}

// ---------------------------------------------------------------------------
extern "C" void kernel_launch(void* const* d_in, const int* in_sizes, int n_in,
                              void* d_out, int out_size, void* d_ws, size_t ws_size,
                              hipStream_t stream) {
  const float* x = (const float*)d_in[0];
  const int* ei = (const int*)d_in[1];
  const int* batch = (const int*)d_in[2];
  const float* W1 = (const float*)d_in[3];
  const float* b1 = (const float*)d_in[4];
  const float* W2 = (const float*)d_in[5];
  const float* b2 = (const float*)d_in[6];
  const float* Wg = (const float*)d_in[7];
  const float* att_src = (const float*)d_in[8];
  const float* att_dst = (const float*)d_in[9];
  const float* bg = (const float*)d_in[10];
  const float* W_heads = (const float*)d_in[11];
  const float* b_heads = (const float*)d_in[12];
  float* out = (float*)d_out;

  const int N = in_sizes[0] / IN_DIM;   // 10000
  const int E = in_sizes[1] / 2;        // 160000
  const int* src = ei;
  const int* dst = ei + E;

  const int NFM = N / 16;               // 625
  const int NFMP = ((N + 63) / 64) * 4; // 628

  // workspace layout (256B aligned); cnt|cursor contiguous for 1 memset
  char* ws = (char*)d_ws;
  size_t off = 0;
  auto take = [&](size_t bytes) -> char* {
    char* p = ws + off;
    off = (off + bytes + 255) & ~(size_t)255;
    return p;
  };
  int* cnt      = (int*)take((size_t)N * 4);
  int* cursor   = (int*)take((size_t)N * 4);
  size_t zero_span = off;
  int* row_ptr  = (int*)take((size_t)(N + 1) * 4);
  int* csr_src  = (int*)take((size_t)E * 4);
  float* dinv   = (float*)take((size_t)N * 4);
  float4* a_src4 = (float4*)take((size_t)N * 16);
  float4* a_dst4 = (float4*)take((size_t)N * 16);
  float* w_s    = (float*)take((size_t)HID * NHEADS * 4);
  float* w_d    = (float*)take((size_t)HID * NHEADS * 4);
  u16*   tb     = (u16*)take((size_t)N * HID * 2);
  float* h3     = (float*)take((size_t)N * HID * 4);
  u16*   hgT    = (u16*)take((size_t)N * NHEADS * HID * 2);   // node-major [n][1024]
  u16*   xp     = (u16*)take((size_t)NFMP * 4 * 1024 * 2);
  u16*   h1p    = (u16*)take((size_t)NFMP * 8 * 1024 * 2);
  u16*   h2p    = (u16*)take((size_t)NFMP * 8 * 1024 * 2);
  u16*   w1p    = (u16*)take((size_t)16 * 4 * 1024 * 2);
  u16*   w2p    = (u16*)take((size_t)16 * 8 * 1024 * 2);
  u16*   wgp    = (u16*)take((size_t)64 * 8 * 1024 * 2);

  hipMemsetAsync(cnt, 0, zero_span, stream);

  int eb = (E + 255) / 256;
  count_edges_k<<<eb, 256, 0, stream>>>(dst, cnt, E);
  // prep: block0 = scan, then packs + watt + tail (out := bias)
  prep_k<<<1 + NFM + 432 + 1, 256, 0, stream>>>(x, W1, W2, Wg, att_src, att_dst,
                                                cnt, row_ptr, dinv,
                                                xp, w1p, w2p, wgp, w_s, w_d,
                                                b_heads, out, NFM, N);
  fill_csr_k<<<eb, 256, 0, stream>>>(src, dst, row_ptr, cursor, csr_src, E);

  int mg64 = (N + 63) / 64;
  int ng4 = (N + 3) / 4;
  int ng2 = (N + 1) / 2;
  // layer 1
  mfma_gemm_k<4, HID><<<dim3(4, mg64), 256, 0, stream>>>(xp, w1p, tb, N);
  gcn_agg_k<false><<<ng4, 256, 0, stream>>>(tb, row_ptr, csr_src, dinv, b1,
                                            h1p, nullptr, nullptr, nullptr, nullptr, N);
  // layer 2 (+ fused logits)
  mfma_gemm_k<8, HID><<<dim3(4, mg64), 256, 0, stream>>>(h1p, w2p, tb, N);
  gcn_agg_k<true><<<ng4, 256, 0, stream>>>(tb, row_ptr, csr_src, dinv, b2,
                                           h2p, w_s, w_d, a_src4, a_dst4, N);
  // GAT
  mfma_gemm_k<8, NHEADS * HID><<<dim3(16, mg64), 256, 0, stream>>>(h2p, wgp, hgT, N);
  gat_agg_k<<<ng2, 256, 0, stream>>>(hgT, row_ptr, csr_src, a_src4, a_dst4, bg, h3, N);
  // fused pool + head
  pool_head_k<<<NGRAPHS * 8, 256, 0, stream>>>(h3, batch, W_heads, out, N);
}